// Round 1
// baseline (1015.967 us; speedup 1.0000x reference)
//
#include <hip/hip_runtime.h>

// SlotAttention, algebraically restructured:
//   logits = (LN(slots) @ (Wq^T @ Wk)) . x / 16   (q.bk term dropped: softmax-invariant)
//   updates = softmax-weighted-avg(x) @ Wv^T + bv  (attn rows sum to 1)
// -> k, v are never materialized. x is converted to bf16 once (L3-resident for iters 2,3).

constexpr int Bn = 64;    // batch
constexpr int Nn = 4096;  // inputs per batch
constexpr int Dd = 256;   // feature dim (== IN_D)
constexpr int Ss = 8;     // slots
constexpr int CH = 16;    // N-chunks per batch for attention
constexpr float EPSF = 1e-5f;

#define DEV __device__ __forceinline__

DEV unsigned bfpack2(float lo, float hi) {
  unsigned ul = __float_as_uint(lo), uh = __float_as_uint(hi);
  ul = (ul + 0x7FFFu + ((ul >> 16) & 1u)) >> 16;         // RNE to bf16
  uh = (uh + 0x7FFFu + ((uh >> 16) & 1u)) & 0xFFFF0000u;
  return ul | uh;
}
DEV float2 bfunpack2(unsigned u) {
  return make_float2(__uint_as_float(u << 16), __uint_as_float(u & 0xFFFF0000u));
}
DEV float wave_sum(float v) {
#pragma unroll
  for (int off = 32; off > 0; off >>= 1) v += __shfl_down(v, off, 64);
  return v;
}

// ---------------- init slots = mu + sigma*noise ----------------
__global__ __launch_bounds__(256) void k_init(const float* __restrict__ noise,
                                              const float* __restrict__ mu,
                                              const float* __restrict__ sg,
                                              float* __restrict__ slots) {
  int i = blockIdx.x * 256 + threadIdx.x;  // float4 index; 32768 total
  float4 nz = ((const float4*)noise)[i];
  int m = i & 511;  // broadcast over batch: 2048 floats = 512 float4
  float4 m4 = ((const float4*)mu)[m];
  float4 s4 = ((const float4*)sg)[m];
  float4 o;
  o.x = m4.x + s4.x * nz.x; o.y = m4.y + s4.y * nz.y;
  o.z = m4.z + s4.z * nz.z; o.w = m4.w + s4.w * nz.w;
  ((float4*)slots)[i] = o;
}

// ---------------- WqkT[c][d] = sum_e Wq[e][d]*Wk[e][c]; bqk[c] = sum_e bq[e]*Wk[e][c] ----
__global__ __launch_bounds__(256) void k_wqk(const float* __restrict__ Wq,
                                             const float* __restrict__ Wk,
                                             const float* __restrict__ bq,
                                             float* __restrict__ WqkT,
                                             float* __restrict__ bqk) {
  int tid = threadIdx.x, c = blockIdx.x;
  if (c < 256) {
    float acc = 0.f;
    for (int e = 0; e < 256; ++e) acc += Wq[e * 256 + tid] * Wk[e * 256 + c];
    WqkT[c * 256 + tid] = acc;
  } else {
    float acc = 0.f;
    for (int e = 0; e < 256; ++e) acc += bq[e] * Wk[e * 256 + tid];
    bqk[tid] = acc;
  }
}

// ---------------- small GEMM: out[row][j] (=|+=) sum_k in[row][k]*W[j][k] + bias[j] ----
// rows=4 (in: LDS [4][256]); 512 threads; W tiled 32 rows through LDS (transposed, stride 33
// -> conflict-free staging writes AND compute reads). Weight is streamed from L2.
template <bool ACC>
__device__ __forceinline__ void small_gemm(const float* __restrict__ W,
                                           const float* __restrict__ bias, int ncols,
                                           const float* __restrict__ in,
                                           float* __restrict__ out, int ldo,
                                           float* __restrict__ wt,  // LDS [256*33]
                                           float* __restrict__ hc,  // LDS [8*4*32]
                                           int tid) {
  const int jj = tid & 31;
  const int ks = (tid >> 5) & 7;  // k-split 8 x 32
  const int rg = tid >> 8;        // row group 0..1 (2 rows each)
  for (int j0 = 0; j0 < ncols; j0 += 32) {
    const float* Wg = W + j0 * 256;
#pragma unroll
    for (int i = 0; i < 16; ++i) {  // stage 32x256 tile, transposed into wt[kf*33+jw]
      int flat = i * 512 + tid;
      int jw = flat >> 8, kf = flat & 255;
      wt[kf * 33 + jw] = Wg[jw * 256 + kf];
    }
    __syncthreads();
    float a0 = 0.f, a1 = 0.f;
    const float* i0 = in + (rg * 2) * 256 + ks * 32;
    const float* i1 = i0 + 256;
    const float* wc = wt + (ks * 32) * 33 + jj;
#pragma unroll
    for (int k = 0; k < 32; k += 4) {
      float4 x0 = *(const float4*)(i0 + k);
      float4 x1 = *(const float4*)(i1 + k);
      float w0 = wc[(k + 0) * 33], w1 = wc[(k + 1) * 33];
      float w2 = wc[(k + 2) * 33], w3 = wc[(k + 3) * 33];
      a0 += x0.x * w0 + x0.y * w1 + x0.z * w2 + x0.w * w3;
      a1 += x1.x * w0 + x1.y * w1 + x1.z * w2 + x1.w * w3;
    }
    hc[(ks * 4 + rg * 2 + 0) * 32 + jj] = a0;
    hc[(ks * 4 + rg * 2 + 1) * 32 + jj] = a1;
    __syncthreads();
    if (tid < 128) {
      int row = tid >> 5, j = tid & 31;
      float s = bias[j0 + j];
#pragma unroll
      for (int p = 0; p < 8; ++p) s += hc[(p * 4 + row) * 32 + j];
      if (ACC) out[row * ldo + j0 + j] += s;
      else     out[row * ldo + j0 + j] = s;
    }
    __syncthreads();
  }
}

// ---------------- LayerNorm over 4 rows of [256], 512 threads (2 waves/row) ----------
__device__ __forceinline__ void ln4(const float* __restrict__ in, float* __restrict__ out,
                                    const float* __restrict__ g, const float* __restrict__ b,
                                    float* __restrict__ red, int tid) {
  int row = tid >> 7, i = tid & 127;
  float x0 = in[row * 256 + i], x1 = in[row * 256 + 128 + i];
  float s = wave_sum(x0 + x1);
  if ((tid & 63) == 0) red[tid >> 6] = s;
  __syncthreads();
  float mean = (red[row * 2] + red[row * 2 + 1]) * (1.f / 256.f);
  float d0 = x0 - mean, d1 = x1 - mean;
  float ss = wave_sum(d0 * d0 + d1 * d1);
  if ((tid & 63) == 0) red[8 + (tid >> 6)] = ss;
  __syncthreads();
  float var = (red[8 + row * 2] + red[8 + row * 2 + 1]) * (1.f / 256.f);
  float rs = rsqrtf(var + EPSF);
  out[row * 256 + i] = d0 * rs * g[i] + b[i];
  out[row * 256 + 128 + i] = d1 * rs * g[128 + i] + b[128 + i];
  __syncthreads();
}

// ---------------- initial q' (iteration 0): LN(slots) @ WqkT + bqk, scaled 1/16 ------
__global__ __launch_bounds__(512) void k_qk_only(const float* __restrict__ slots,
                                                 const float* __restrict__ g,
                                                 const float* __restrict__ b,
                                                 const float* __restrict__ WqkT,
                                                 const float* __restrict__ bqk,
                                                 float* __restrict__ qk) {
  __shared__ __align__(16) float wt[256 * 33];
  __shared__ __align__(16) float hc[1024];
  __shared__ __align__(16) float srow[1024];
  __shared__ __align__(16) float lnb[1024];
  __shared__ __align__(16) float ob[1024];
  __shared__ float red[16];
  int tid = threadIdx.x;
  int bb = blockIdx.x >> 1, s0 = (blockIdx.x & 1) * 4;
  int rbase = (bb * 8 + s0) * 256;
#pragma unroll
  for (int i = 0; i < 2; ++i) { int f = i * 512 + tid; srow[f] = slots[rbase + f]; }
  __syncthreads();
  ln4(srow, lnb, g, b, red, tid);
  small_gemm<false>(WqkT, bqk, 256, lnb, ob, 256, wt, hc, tid);
#pragma unroll
  for (int i = 0; i < 2; ++i) { int f = i * 512 + tid; qk[rbase + f] = ob[f] * 0.0625f; }
}

// ---------------- attention pass: per (chunk, batch) block ----------------
// logits[r][s] = qk[s].x[r]; p = exp(logit); accumulate l[s], u[s][:] per chunk.
// FIRST: read f32 inputs and also emit the bf16 copy; else read bf16 (L3-resident).
template <bool FIRST>
__global__ __launch_bounds__(256) void k_attn(const float* __restrict__ xin,
                                              unsigned* __restrict__ xbf,
                                              const float* __restrict__ qk,
                                              float* __restrict__ pl,
                                              float* __restrict__ pu) {
  __shared__ __align__(16) float xt[32 * 260];
  __shared__ __align__(16) float qs[8 * 260];
  __shared__ __align__(16) float pt[32 * 8];
  __shared__ float lrun[8];
  const int tid = threadIdx.x;
  const int c = blockIdx.x, b = blockIdx.y;
#pragma unroll
  for (int i = 0; i < 8; ++i) qs[i * 260 + tid] = qk[(b * 8 + i) * 256 + tid];
  if (tid < 8) lrun[tid] = 0.f;
  float u[8];
#pragma unroll
  for (int s = 0; s < 8; ++s) u[s] = 0.f;
  __syncthreads();
  const int r = tid >> 3, s8 = tid & 7;
  for (int tile = 0; tile < 8; ++tile) {
    const int nbase = b * Nn + c * 256 + tile * 32;
    if (FIRST) {
      const float4* src = (const float4*)(xin + (size_t)nbase * 256);
#pragma unroll
      for (int ii = 0; ii < 4; ++ii) {
        float4 v0 = src[ii * 512 + tid * 2];
        float4 v1 = src[ii * 512 + tid * 2 + 1];
        int row = ii * 8 + (tid >> 5), col = (tid & 31) * 8;
        *(float4*)(xt + row * 260 + col) = v0;
        *(float4*)(xt + row * 260 + col + 4) = v1;
        uint4 o;
        o.x = bfpack2(v0.x, v0.y); o.y = bfpack2(v0.z, v0.w);
        o.z = bfpack2(v1.x, v1.y); o.w = bfpack2(v1.z, v1.w);
        ((uint4*)xbf)[nbase * 32 + ii * 256 + tid] = o;
      }
    } else {
#pragma unroll
      for (int ii = 0; ii < 4; ++ii) {
        uint4 v = ((const uint4*)xbf)[nbase * 32 + ii * 256 + tid];
        float2 f0 = bfunpack2(v.x), f1 = bfunpack2(v.y);
        float2 f2 = bfunpack2(v.z), f3 = bfunpack2(v.w);
        int row = ii * 8 + (tid >> 5), col = (tid & 31) * 8;
        *(float4*)(xt + row * 260 + col) = make_float4(f0.x, f0.y, f1.x, f1.y);
        *(float4*)(xt + row * 260 + col + 4) = make_float4(f2.x, f2.y, f3.x, f3.y);
      }
    }
    __syncthreads();
    {  // logits: one (row, slot) dot per thread
      const float* xr = xt + r * 260;
      const float* qr = qs + s8 * 260;
      float acc = 0.f;
#pragma unroll 4
      for (int k = 0; k < 256; k += 8) {
        float4 a0 = *(const float4*)(xr + k);
        float4 a1 = *(const float4*)(xr + k + 4);
        float4 q0 = *(const float4*)(qr + k);
        float4 q1 = *(const float4*)(qr + k + 4);
        acc += a0.x * q0.x + a0.y * q0.y + a0.z * q0.z + a0.w * q0.w +
               a1.x * q1.x + a1.y * q1.y + a1.z * q1.z + a1.w * q1.w;
      }
      pt[tid] = __expf(acc);  // |logit| small (q from LN'd slots): no max-shift needed
    }
    __syncthreads();
    if (tid < 8) {
      float ls = 0.f;
#pragma unroll
      for (int rr = 0; rr < 32; ++rr) ls += pt[rr * 8 + tid];
      lrun[tid] += ls;
    }
#pragma unroll 4
    for (int rr = 0; rr < 32; ++rr) {  // u[s][col=tid] += p[rr][s]*x[rr][col]
      float4 p0 = *(const float4*)(pt + rr * 8);
      float4 p1 = *(const float4*)(pt + rr * 8 + 4);
      float xv = xt[rr * 260 + tid];
      u[0] += p0.x * xv; u[1] += p0.y * xv; u[2] += p0.z * xv; u[3] += p0.w * xv;
      u[4] += p1.x * xv; u[5] += p1.y * xv; u[6] += p1.z * xv; u[7] += p1.w * xv;
    }
    __syncthreads();
  }
  const int pb = (b * CH + c) * 8;
#pragma unroll
  for (int s = 0; s < 8; ++s) pu[(pb + s) * 256 + tid] = u[s];
  if (tid < 8) pl[pb + tid] = lrun[tid];
}

// ---------------- combine chunks + updates@Wv^T + GRU + residual -> slots -----------
__global__ __launch_bounds__(512) void k_gru(const float* __restrict__ pl,
                                             const float* __restrict__ pu,
                                             const float* __restrict__ Wv,
                                             const float* __restrict__ bv,
                                             const float* __restrict__ Wih,
                                             const float* __restrict__ bih,
                                             const float* __restrict__ Whh,
                                             const float* __restrict__ bhh,
                                             float* __restrict__ slots) {
  __shared__ __align__(16) float wt[256 * 33];
  __shared__ __align__(16) float hc[1024];
  __shared__ __align__(16) float up[1024];   // u' (weighted avg of x)
  __shared__ __align__(16) float ub[1024];   // updates, later h_n
  __shared__ __align__(16) float sp[1024];   // slots_prev
  __shared__ __align__(16) float gib[3072];  // gi (+ gh for r,z)
  __shared__ float linv[4];
  int tid = threadIdx.x;
  int bb = blockIdx.x >> 1, s0 = (blockIdx.x & 1) * 4;
  int rbase = (bb * 8 + s0) * 256;
#pragma unroll
  for (int i = 0; i < 2; ++i) { int f = i * 512 + tid; sp[f] = slots[rbase + f]; }
  if (tid < 4) {
    float L = 0.f;
    for (int cc = 0; cc < CH; ++cc) L += pl[(bb * CH + cc) * 8 + s0 + tid];
    linv[tid] = 1.f / L;
  }
  __syncthreads();
  {
    int row = tid >> 7, c2 = (tid & 127) * 2;
    float a0 = 0.f, a1 = 0.f;
    for (int cc = 0; cc < CH; ++cc) {
      float2 v = *(const float2*)(pu + ((bb * CH + cc) * 8 + s0 + row) * 256 + c2);
      a0 += v.x; a1 += v.y;
    }
    *(float2*)(up + row * 256 + c2) = make_float2(a0 * linv[row], a1 * linv[row]);
  }
  __syncthreads();
  small_gemm<false>(Wv, bv, 256, up, ub, 256, wt, hc, tid);                // updates
  small_gemm<false>(Wih, bih, 768, ub, gib, 768, wt, hc, tid);             // gi
  small_gemm<true>(Whh, bhh, 512, sp, gib, 768, wt, hc, tid);              // + gh (r,z)
  small_gemm<false>(Whh + 512 * 256, bhh + 512, 256, sp, ub, 256, wt, hc, tid);  // h_n
#pragma unroll
  for (int i = 0; i < 2; ++i) {
    int f = i * 512 + tid, row = f >> 8, d = f & 255;
    float rr = 1.f / (1.f + __expf(-gib[row * 768 + d]));
    float zz = 1.f / (1.f + __expf(-gib[row * 768 + 256 + d]));
    float nin = gib[row * 768 + 512 + d] + rr * ub[row * 256 + d];
    float nn = 1.f - 2.f / (__expf(2.f * nin) + 1.f);  // tanh
    float hp = sp[row * 256 + d];
    slots[rbase + f] = hp + (1.f - zz) * nn + zz * hp;  // prev + h_new
  }
}

// ---------------- MLP (+residual) + next-iteration q' ----------------
__global__ __launch_bounds__(512) void k_mlp(const float* __restrict__ W1,
                                             const float* __restrict__ b1,
                                             const float* __restrict__ W2,
                                             const float* __restrict__ b2,
                                             const float* __restrict__ gm,
                                             const float* __restrict__ bm,
                                             const float* __restrict__ gs,
                                             const float* __restrict__ bs,
                                             const float* __restrict__ WqkT,
                                             const float* __restrict__ bqk,
                                             float* __restrict__ slots,
                                             float* __restrict__ qk,
                                             float* __restrict__ dout) {
  __shared__ __align__(16) float wt[256 * 33];
  __shared__ __align__(16) float hc[1024];
  __shared__ __align__(16) float srow[1024];
  __shared__ __align__(16) float lnb[1024];
  __shared__ __align__(16) float hid[1024];
  __shared__ __align__(16) float sn[1024];
  __shared__ float red[16];
  int tid = threadIdx.x;
  int bb = blockIdx.x >> 1, s0 = (blockIdx.x & 1) * 4;
  int rbase = (bb * 8 + s0) * 256;
#pragma unroll
  for (int i = 0; i < 2; ++i) { int f = i * 512 + tid; srow[f] = slots[rbase + f]; }
  __syncthreads();
  ln4(srow, lnb, gm, bm, red, tid);
  small_gemm<false>(W1, b1, 256, lnb, hid, 256, wt, hc, tid);
#pragma unroll
  for (int i = 0; i < 2; ++i) { int f = i * 512 + tid; hid[f] = fmaxf(hid[f], 0.f); }
  __syncthreads();
  small_gemm<false>(W2, b2, 256, hid, sn, 256, wt, hc, tid);
#pragma unroll
  for (int i = 0; i < 2; ++i) {
    int f = i * 512 + tid;
    float v = sn[f] + srow[f];
    sn[f] = v;
    slots[rbase + f] = v;
    if (dout) dout[rbase + f] = v;
  }
  __syncthreads();
  ln4(sn, lnb, gs, bs, red, tid);
  small_gemm<false>(WqkT, bqk, 256, lnb, hid, 256, wt, hc, tid);
#pragma unroll
  for (int i = 0; i < 2; ++i) { int f = i * 512 + tid; qk[rbase + f] = hid[f] * 0.0625f; }
}

// ---------------- launch ----------------
extern "C" void kernel_launch(void* const* d_in, const int* in_sizes, int n_in,
                              void* d_out, int out_size, void* d_ws, size_t ws_size,
                              hipStream_t stream) {
  const float* inputs = (const float*)d_in[0];
  const float* noise = (const float*)d_in[1];
  const float* s_mu = (const float*)d_in[2];
  const float* s_sg = (const float*)d_in[3];
  const float* Wq = (const float*)d_in[4];
  const float* bq = (const float*)d_in[5];
  const float* Wk = (const float*)d_in[6];
  // d_in[7] = bk: unused — q.bk is constant over n, softmax-invariant.
  const float* Wv = (const float*)d_in[8];
  const float* bv = (const float*)d_in[9];
  const float* Wih = (const float*)d_in[10];
  const float* bih = (const float*)d_in[11];
  const float* Whh = (const float*)d_in[12];
  const float* bhh = (const float*)d_in[13];
  const float* W1 = (const float*)d_in[14];
  const float* b1 = (const float*)d_in[15];
  const float* W2 = (const float*)d_in[16];
  const float* b2 = (const float*)d_in[17];
  const float* gsl = (const float*)d_in[18];
  const float* bsl = (const float*)d_in[19];
  const float* gml = (const float*)d_in[20];
  const float* bml = (const float*)d_in[21];
  float* out = (float*)d_out;

  char* wsb = (char*)d_ws;
  unsigned* xbf = (unsigned*)wsb;  // bf16 copy of inputs: 64*4096*256*2 B = 128 MiB
  float* fp = (float*)(wsb + (size_t)Bn * Nn * Dd * 2);
  float* slots = fp; fp += Bn * Ss * Dd;
  float* qk = fp;    fp += Bn * Ss * Dd;
  float* WqkT = fp;  fp += Dd * Dd;
  float* bqk = fp;   fp += Dd;
  float* pl = fp;    fp += Bn * CH * Ss;
  float* pu = fp;    fp += Bn * CH * Ss * Dd;
  (void)in_sizes; (void)n_in; (void)out_size; (void)ws_size;

  k_init<<<dim3(128), dim3(256), 0, stream>>>(noise, s_mu, s_sg, slots);
  k_wqk<<<dim3(257), dim3(256), 0, stream>>>(Wq, Wk, bq, WqkT, bqk);
  k_qk_only<<<dim3(128), dim3(512), 0, stream>>>(slots, gsl, bsl, WqkT, bqk, qk);
  for (int it = 0; it < 3; ++it) {
    if (it == 0)
      k_attn<true><<<dim3(CH, Bn), dim3(256), 0, stream>>>(inputs, xbf, qk, pl, pu);
    else
      k_attn<false><<<dim3(CH, Bn), dim3(256), 0, stream>>>(nullptr, xbf, qk, pl, pu);
    k_gru<<<dim3(128), dim3(512), 0, stream>>>(pl, pu, Wv, bv, Wih, bih, Whh, bhh, slots);
    k_mlp<<<dim3(128), dim3(512), 0, stream>>>(W1, b1, W2, b2, gml, bml, gsl, bsl, WqkT,
                                               bqk, slots, qk, (it == 2) ? out : nullptr);
  }
}

// Round 2
// 919.171 us; speedup vs baseline: 1.1053x; 1.1053x over previous
//
#include <hip/hip_runtime.h>

// SlotAttention, algebraically restructured:
//   logits = (LN(slots) @ (Wq^T @ Wk)) . x / 16   (q.bk term dropped: softmax-invariant)
//   updates = softmax-weighted-avg(x) @ Wv^T + bv  (attn rows sum to 1)
// -> k, v are never materialized. x is converted to bf16 once (L3-resident for iters 2,3).
// R2: attention rewritten on MFMA (16x16x32 bf16): P^T = q@X^T, U^T = X^T@P,
//     X^T staged in LDS d-pair-packed (stride 33).

constexpr int Bn = 64;    // batch
constexpr int Nn = 4096;  // inputs per batch
constexpr int Dd = 256;   // feature dim (== IN_D)
constexpr int Ss = 8;     // slots
constexpr int CH = 16;    // N-chunks per batch for attention
constexpr float EPSF = 1e-5f;

#define DEV __device__ __forceinline__

using short8 = __attribute__((ext_vector_type(8))) short;
using f32x4 = __attribute__((ext_vector_type(4))) float;
union U8 { short8 s; uint4 u; };

DEV unsigned bfpack2(float lo, float hi) {
  unsigned ul = __float_as_uint(lo), uh = __float_as_uint(hi);
  ul = (ul + 0x7FFFu + ((ul >> 16) & 1u)) >> 16;         // RNE to bf16
  uh = (uh + 0x7FFFu + ((uh >> 16) & 1u)) & 0xFFFF0000u;
  return ul | uh;
}
DEV unsigned short bf16r(float x) {
  unsigned u = __float_as_uint(x);
  u = (u + 0x7FFFu + ((u >> 16) & 1u)) >> 16;
  return (unsigned short)u;
}
DEV float wave_sum(float v) {
#pragma unroll
  for (int off = 32; off > 0; off >>= 1) v += __shfl_down(v, off, 64);
  return v;
}

// ---------------- init slots = mu + sigma*noise ----------------
__global__ __launch_bounds__(256) void k_init(const float* __restrict__ noise,
                                              const float* __restrict__ mu,
                                              const float* __restrict__ sg,
                                              float* __restrict__ slots) {
  int i = blockIdx.x * 256 + threadIdx.x;  // float4 index; 32768 total
  float4 nz = ((const float4*)noise)[i];
  int m = i & 511;  // broadcast over batch: 2048 floats = 512 float4
  float4 m4 = ((const float4*)mu)[m];
  float4 s4 = ((const float4*)sg)[m];
  float4 o;
  o.x = m4.x + s4.x * nz.x; o.y = m4.y + s4.y * nz.y;
  o.z = m4.z + s4.z * nz.z; o.w = m4.w + s4.w * nz.w;
  ((float4*)slots)[i] = o;
}

// ---------------- WqkT[c][d] = sum_e Wq[e][d]*Wk[e][c]; bqk[c] = sum_e bq[e]*Wk[e][c] ----
__global__ __launch_bounds__(256) void k_wqk(const float* __restrict__ Wq,
                                             const float* __restrict__ Wk,
                                             const float* __restrict__ bq,
                                             float* __restrict__ WqkT,
                                             float* __restrict__ bqk) {
  int tid = threadIdx.x, c = blockIdx.x;
  if (c < 256) {
    float acc = 0.f;
    for (int e = 0; e < 256; ++e) acc += Wq[e * 256 + tid] * Wk[e * 256 + c];
    WqkT[c * 256 + tid] = acc;
  } else {
    float acc = 0.f;
    for (int e = 0; e < 256; ++e) acc += bq[e] * Wk[e * 256 + tid];
    bqk[tid] = acc;
  }
}

// ---------------- small GEMM: out[row][j] (=|+=) sum_k in[row][k]*W[j][k] + bias[j] ----
template <bool ACC>
__device__ __forceinline__ void small_gemm(const float* __restrict__ W,
                                           const float* __restrict__ bias, int ncols,
                                           const float* __restrict__ in,
                                           float* __restrict__ out, int ldo,
                                           float* __restrict__ wt,  // LDS [256*33]
                                           float* __restrict__ hc,  // LDS [8*4*32]
                                           int tid) {
  const int jj = tid & 31;
  const int ks = (tid >> 5) & 7;  // k-split 8 x 32
  const int rg = tid >> 8;        // row group 0..1 (2 rows each)
  for (int j0 = 0; j0 < ncols; j0 += 32) {
    const float* Wg = W + j0 * 256;
#pragma unroll
    for (int i = 0; i < 16; ++i) {  // stage 32x256 tile, transposed into wt[kf*33+jw]
      int flat = i * 512 + tid;
      int jw = flat >> 8, kf = flat & 255;
      wt[kf * 33 + jw] = Wg[jw * 256 + kf];
    }
    __syncthreads();
    float a0 = 0.f, a1 = 0.f;
    const float* i0 = in + (rg * 2) * 256 + ks * 32;
    const float* i1 = i0 + 256;
    const float* wc = wt + (ks * 32) * 33 + jj;
#pragma unroll
    for (int k = 0; k < 32; k += 4) {
      float4 x0 = *(const float4*)(i0 + k);
      float4 x1 = *(const float4*)(i1 + k);
      float w0 = wc[(k + 0) * 33], w1 = wc[(k + 1) * 33];
      float w2 = wc[(k + 2) * 33], w3 = wc[(k + 3) * 33];
      a0 += x0.x * w0 + x0.y * w1 + x0.z * w2 + x0.w * w3;
      a1 += x1.x * w0 + x1.y * w1 + x1.z * w2 + x1.w * w3;
    }
    hc[(ks * 4 + rg * 2 + 0) * 32 + jj] = a0;
    hc[(ks * 4 + rg * 2 + 1) * 32 + jj] = a1;
    __syncthreads();
    if (tid < 128) {
      int row = tid >> 5, j = tid & 31;
      float s = bias[j0 + j];
#pragma unroll
      for (int p = 0; p < 8; ++p) s += hc[(p * 4 + row) * 32 + j];
      if (ACC) out[row * ldo + j0 + j] += s;
      else     out[row * ldo + j0 + j] = s;
    }
    __syncthreads();
  }
}

// ---------------- LayerNorm over 4 rows of [256], 512 threads (2 waves/row) ----------
__device__ __forceinline__ void ln4(const float* __restrict__ in, float* __restrict__ out,
                                    const float* __restrict__ g, const float* __restrict__ b,
                                    float* __restrict__ red, int tid) {
  int row = tid >> 7, i = tid & 127;
  float x0 = in[row * 256 + i], x1 = in[row * 256 + 128 + i];
  float s = wave_sum(x0 + x1);
  if ((tid & 63) == 0) red[tid >> 6] = s;
  __syncthreads();
  float mean = (red[row * 2] + red[row * 2 + 1]) * (1.f / 256.f);
  float d0 = x0 - mean, d1 = x1 - mean;
  float ss = wave_sum(d0 * d0 + d1 * d1);
  if ((tid & 63) == 0) red[8 + (tid >> 6)] = ss;
  __syncthreads();
  float var = (red[8 + row * 2] + red[8 + row * 2 + 1]) * (1.f / 256.f);
  float rs = rsqrtf(var + EPSF);
  out[row * 256 + i] = d0 * rs * g[i] + b[i];
  out[row * 256 + 128 + i] = d1 * rs * g[128 + i] + b[128 + i];
  __syncthreads();
}

// ---------------- initial q' (iteration 0): LN(slots) @ WqkT + bqk, scaled 1/16 ------
__global__ __launch_bounds__(512) void k_qk_only(const float* __restrict__ slots,
                                                 const float* __restrict__ g,
                                                 const float* __restrict__ b,
                                                 const float* __restrict__ WqkT,
                                                 const float* __restrict__ bqk,
                                                 float* __restrict__ qk) {
  __shared__ __align__(16) float wt[256 * 33];
  __shared__ __align__(16) float hc[1024];
  __shared__ __align__(16) float srow[1024];
  __shared__ __align__(16) float lnb[1024];
  __shared__ __align__(16) float ob[1024];
  __shared__ float red[16];
  int tid = threadIdx.x;
  int bb = blockIdx.x >> 1, s0 = (blockIdx.x & 1) * 4;
  int rbase = (bb * 8 + s0) * 256;
#pragma unroll
  for (int i = 0; i < 2; ++i) { int f = i * 512 + tid; srow[f] = slots[rbase + f]; }
  __syncthreads();
  ln4(srow, lnb, g, b, red, tid);
  small_gemm<false>(WqkT, bqk, 256, lnb, ob, 256, wt, hc, tid);
#pragma unroll
  for (int i = 0; i < 2; ++i) { int f = i * 512 + tid; qk[rbase + f] = ob[f] * 0.0625f; }
}

// ---------------- MFMA attention pass: per (chunk, batch) block ----------------
// Per 32-row sub-chunk:
//  stage: X^T pair-packed over d into LDS xt[128 pair-rows][33] (uint = (bf16 d_even, d_odd))
//  phase A (waves 0,1): P^T[s][xrow] = q @ X^T  (8 MFMAs, K=256); exp in C-layout regs;
//                       l-partials in regs; P -> LDS pp pair-packed over n.
//  phase B (all waves): U^T[d][s] += X^T @ P  (wave owns 64 d = 4 tiles, K=32), acc in AGPRs.
// FIRST: read f32 inputs, emit bf16 copy xbf; else read xbf (L3-resident).
template <bool FIRST>
__global__ __launch_bounds__(256) void k_attn(const float* __restrict__ xin,
                                              unsigned* __restrict__ xbf,
                                              const float* __restrict__ qk,
                                              float* __restrict__ pl,
                                              float* __restrict__ pu) {
  __shared__ unsigned xt[128 * 33];
  __shared__ unsigned pp[16 * 17];
  __shared__ float lred[2][16];
  const int tid = threadIdx.x;
  const int lane = tid & 63, wave = tid >> 6;
  const int m16 = lane & 15, quad = lane >> 4;
  const int c = blockIdx.x, b = blockIdx.y;
  const int pb = (b * CH + c) * 8;

  // q A-frags: lane holds q[s=m16][k=quad*8+j] per 32-wide K step (s>=8 -> zero)
  short8 aq[8];
  {
    const float* qrow = qk + (size_t)(b * 8 + (m16 & 7)) * 256 + quad * 8;
#pragma unroll
    for (int kk = 0; kk < 8; ++kk) {
      U8 f;
      float4 q0 = *(const float4*)(qrow + kk * 32);
      float4 q1 = *(const float4*)(qrow + kk * 32 + 4);
      f.u.x = bfpack2(q0.x, q0.y); f.u.y = bfpack2(q0.z, q0.w);
      f.u.z = bfpack2(q1.x, q1.y); f.u.w = bfpack2(q1.z, q1.w);
      if (m16 >= 8) { f.u.x = 0u; f.u.y = 0u; f.u.z = 0u; f.u.w = 0u; }
      aq[kk] = f.s;
    }
  }
  float lacc[4] = {0.f, 0.f, 0.f, 0.f};
  f32x4 acc[4];
#pragma unroll
  for (int t = 0; t < 4; ++t) acc[t] = (f32x4){0.f, 0.f, 0.f, 0.f};

  const int d0w = wave * 64;
  for (int ch = 0; ch < 8; ++ch) {
    const size_t nbase = (size_t)b * Nn + (size_t)c * 256 + ch * 32;
    // ---- stage 32 rows x 256 d as X^T pair-packed ----
#pragma unroll
    for (int i = 0; i < 4; ++i) {
      int flat = i * 256 + tid;          // 0..1023
      int n = flat >> 5, od = flat & 31; // row-in-chunk, d-octet
      uint4 pr;
      if (FIRST) {
        const float4* src = (const float4*)(xin + (nbase + n) * 256 + od * 8);
        float4 v0 = src[0], v1 = src[1];
        pr.x = bfpack2(v0.x, v0.y); pr.y = bfpack2(v0.z, v0.w);
        pr.z = bfpack2(v1.x, v1.y); pr.w = bfpack2(v1.z, v1.w);
        ((uint4*)xbf)[(nbase + n) * 32 + od] = pr;
      } else {
        pr = ((const uint4*)xbf)[(nbase + n) * 32 + od];
      }
      int rb = od * 4;  // pair-row base (d0/2)
      xt[(rb + 0) * 33 + n] = pr.x;
      xt[(rb + 1) * 33 + n] = pr.y;
      xt[(rb + 2) * 33 + n] = pr.z;
      xt[(rb + 3) * 33 + n] = pr.w;
    }
    __syncthreads();
    // ---- phase A: logits + exp + P ----
    if (wave < 2) {
      f32x4 pacc = (f32x4){0.f, 0.f, 0.f, 0.f};
#pragma unroll
      for (int kk = 0; kk < 8; ++kk) {
        // B[k=d][n=xrow]: pair-rows kk*16+quad*4+(0..3), col = wave*16+m16
        int base = (kk * 16 + quad * 4) * 33 + wave * 16 + m16;
        U8 bf;
        bf.u.x = xt[base]; bf.u.y = xt[base + 33];
        bf.u.z = xt[base + 66]; bf.u.w = xt[base + 99];
        pacc = __builtin_amdgcn_mfma_f32_16x16x32_bf16(aq[kk], bf.s, pacc, 0, 0, 0);
      }
      const int xrow = wave * 16 + m16;
      unsigned short* pps = (unsigned short*)pp;
#pragma unroll
      for (int r = 0; r < 4; ++r) {
        // C-layout: row(s) = quad*4+r, col(xrow) = m16. s>=8 rows: q=0 -> exp(0)=1, unused.
        float p = __expf(pacc[r]);
        lacc[r] += p;
        pps[((xrow >> 1) * 17 + quad * 4 + r) * 2 + (xrow & 1)] = bf16r(p);
      }
    }
    __syncthreads();
    // ---- phase B: U^T += X^T @ P ----
    U8 bp;  // B[k=n][s]: pair-rows quad*4+(0..3), col s=m16
    bp.u.x = pp[(quad * 4 + 0) * 17 + m16];
    bp.u.y = pp[(quad * 4 + 1) * 17 + m16];
    bp.u.z = pp[(quad * 4 + 2) * 17 + m16];
    bp.u.w = pp[(quad * 4 + 3) * 17 + m16];
#pragma unroll
    for (int t = 0; t < 4; ++t) {
      int d = d0w + t * 16 + m16;
      int h = d >> 1, sel = d & 1;
      const unsigned* xr = xt + h * 33 + quad * 8;  // A[m=d][k=n]: 8 n-consecutive halves
      unsigned u0 = xr[0], u1 = xr[1], u2 = xr[2], u3 = xr[3];
      unsigned u4 = xr[4], u5 = xr[5], u6 = xr[6], u7 = xr[7];
      U8 af;
      if (sel) {
        af.u.x = (u0 >> 16) | (u1 & 0xFFFF0000u);
        af.u.y = (u2 >> 16) | (u3 & 0xFFFF0000u);
        af.u.z = (u4 >> 16) | (u5 & 0xFFFF0000u);
        af.u.w = (u6 >> 16) | (u7 & 0xFFFF0000u);
      } else {
        af.u.x = (u0 & 0xFFFFu) | (u1 << 16);
        af.u.y = (u2 & 0xFFFFu) | (u3 << 16);
        af.u.z = (u4 & 0xFFFFu) | (u5 << 16);
        af.u.w = (u6 & 0xFFFFu) | (u7 << 16);
      }
      acc[t] = __builtin_amdgcn_mfma_f32_16x16x32_bf16(af.s, bp.s, acc[t], 0, 0, 0);
    }
    __syncthreads();
  }
  // ---- store U (C-layout: row d = quad*4+r within tile, col s = m16) ----
  if (m16 < 8) {
#pragma unroll
    for (int t = 0; t < 4; ++t) {
#pragma unroll
      for (int r = 0; r < 4; ++r) {
        pu[(size_t)(pb + m16) * 256 + d0w + t * 16 + quad * 4 + r] = acc[t][r];
      }
    }
  }
  // ---- l reduction: sum over cols (xrow) within wave, then across waves 0,1 ----
  if (wave < 2) {
#pragma unroll
    for (int r = 0; r < 4; ++r) {
      float v = lacc[r];
      v += __shfl_xor(v, 1); v += __shfl_xor(v, 2);
      v += __shfl_xor(v, 4); v += __shfl_xor(v, 8);
      if (m16 == 0) lred[wave][quad * 4 + r] = v;
    }
  }
  __syncthreads();
  if (tid < 8) pl[pb + tid] = lred[0][tid] + lred[1][tid];
}

// ---------------- combine chunks + updates@Wv^T + GRU + residual -> slots -----------
__global__ __launch_bounds__(512) void k_gru(const float* __restrict__ pl,
                                             const float* __restrict__ pu,
                                             const float* __restrict__ Wv,
                                             const float* __restrict__ bv,
                                             const float* __restrict__ Wih,
                                             const float* __restrict__ bih,
                                             const float* __restrict__ Whh,
                                             const float* __restrict__ bhh,
                                             float* __restrict__ slots) {
  __shared__ __align__(16) float wt[256 * 33];
  __shared__ __align__(16) float hc[1024];
  __shared__ __align__(16) float up[1024];   // u' (weighted avg of x)
  __shared__ __align__(16) float ub[1024];   // updates, later h_n
  __shared__ __align__(16) float sp[1024];   // slots_prev
  __shared__ __align__(16) float gib[3072];  // gi (+ gh for r,z)
  __shared__ float linv[4];
  int tid = threadIdx.x;
  int bb = blockIdx.x >> 1, s0 = (blockIdx.x & 1) * 4;
  int rbase = (bb * 8 + s0) * 256;
#pragma unroll
  for (int i = 0; i < 2; ++i) { int f = i * 512 + tid; sp[f] = slots[rbase + f]; }
  if (tid < 4) {
    float L = 0.f;
    for (int cc = 0; cc < CH; ++cc) L += pl[(bb * CH + cc) * 8 + s0 + tid];
    linv[tid] = 1.f / L;
  }
  __syncthreads();
  {
    int row = tid >> 7, c2 = (tid & 127) * 2;
    float a0 = 0.f, a1 = 0.f;
    for (int cc = 0; cc < CH; ++cc) {
      float2 v = *(const float2*)(pu + ((bb * CH + cc) * 8 + s0 + row) * 256 + c2);
      a0 += v.x; a1 += v.y;
    }
    *(float2*)(up + row * 256 + c2) = make_float2(a0 * linv[row], a1 * linv[row]);
  }
  __syncthreads();
  small_gemm<false>(Wv, bv, 256, up, ub, 256, wt, hc, tid);                // updates
  small_gemm<false>(Wih, bih, 768, ub, gib, 768, wt, hc, tid);             // gi
  small_gemm<true>(Whh, bhh, 512, sp, gib, 768, wt, hc, tid);              // + gh (r,z)
  small_gemm<false>(Whh + 512 * 256, bhh + 512, 256, sp, ub, 256, wt, hc, tid);  // h_n
#pragma unroll
  for (int i = 0; i < 2; ++i) {
    int f = i * 512 + tid, row = f >> 8, d = f & 255;
    float rr = 1.f / (1.f + __expf(-gib[row * 768 + d]));
    float zz = 1.f / (1.f + __expf(-gib[row * 768 + 256 + d]));
    float nin = gib[row * 768 + 512 + d] + rr * ub[row * 256 + d];
    float nn = 1.f - 2.f / (__expf(2.f * nin) + 1.f);  // tanh
    float hp = sp[row * 256 + d];
    slots[rbase + f] = hp + (1.f - zz) * nn + zz * hp;  // prev + h_new
  }
}

// ---------------- MLP (+residual) + next-iteration q' ----------------
__global__ __launch_bounds__(512) void k_mlp(const float* __restrict__ W1,
                                             const float* __restrict__ b1,
                                             const float* __restrict__ W2,
                                             const float* __restrict__ b2,
                                             const float* __restrict__ gm,
                                             const float* __restrict__ bm,
                                             const float* __restrict__ gs,
                                             const float* __restrict__ bs,
                                             const float* __restrict__ WqkT,
                                             const float* __restrict__ bqk,
                                             float* __restrict__ slots,
                                             float* __restrict__ qk,
                                             float* __restrict__ dout) {
  __shared__ __align__(16) float wt[256 * 33];
  __shared__ __align__(16) float hc[1024];
  __shared__ __align__(16) float srow[1024];
  __shared__ __align__(16) float lnb[1024];
  __shared__ __align__(16) float hid[1024];
  __shared__ __align__(16) float sn[1024];
  __shared__ float red[16];
  int tid = threadIdx.x;
  int bb = blockIdx.x >> 1, s0 = (blockIdx.x & 1) * 4;
  int rbase = (bb * 8 + s0) * 256;
#pragma unroll
  for (int i = 0; i < 2; ++i) { int f = i * 512 + tid; srow[f] = slots[rbase + f]; }
  __syncthreads();
  ln4(srow, lnb, gm, bm, red, tid);
  small_gemm<false>(W1, b1, 256, lnb, hid, 256, wt, hc, tid);
#pragma unroll
  for (int i = 0; i < 2; ++i) { int f = i * 512 + tid; hid[f] = fmaxf(hid[f], 0.f); }
  __syncthreads();
  small_gemm<false>(W2, b2, 256, hid, sn, 256, wt, hc, tid);
#pragma unroll
  for (int i = 0; i < 2; ++i) {
    int f = i * 512 + tid;
    float v = sn[f] + srow[f];
    sn[f] = v;
    slots[rbase + f] = v;
    if (dout) dout[rbase + f] = v;
  }
  __syncthreads();
  ln4(sn, lnb, gs, bs, red, tid);
  small_gemm<false>(WqkT, bqk, 256, lnb, hid, 256, wt, hc, tid);
#pragma unroll
  for (int i = 0; i < 2; ++i) { int f = i * 512 + tid; qk[rbase + f] = hid[f] * 0.0625f; }
}

// ---------------- launch ----------------
extern "C" void kernel_launch(void* const* d_in, const int* in_sizes, int n_in,
                              void* d_out, int out_size, void* d_ws, size_t ws_size,
                              hipStream_t stream) {
  const float* inputs = (const float*)d_in[0];
  const float* noise = (const float*)d_in[1];
  const float* s_mu = (const float*)d_in[2];
  const float* s_sg = (const float*)d_in[3];
  const float* Wq = (const float*)d_in[4];
  const float* bq = (const float*)d_in[5];
  const float* Wk = (const float*)d_in[6];
  // d_in[7] = bk: unused — q.bk is constant over n, softmax-invariant.
  const float* Wv = (const float*)d_in[8];
  const float* bv = (const float*)d_in[9];
  const float* Wih = (const float*)d_in[10];
  const float* bih = (const float*)d_in[11];
  const float* Whh = (const float*)d_in[12];
  const float* bhh = (const float*)d_in[13];
  const float* W1 = (const float*)d_in[14];
  const float* b1 = (const float*)d_in[15];
  const float* W2 = (const float*)d_in[16];
  const float* b2 = (const float*)d_in[17];
  const float* gsl = (const float*)d_in[18];
  const float* bsl = (const float*)d_in[19];
  const float* gml = (const float*)d_in[20];
  const float* bml = (const float*)d_in[21];
  float* out = (float*)d_out;

  char* wsb = (char*)d_ws;
  unsigned* xbf = (unsigned*)wsb;  // bf16 copy of inputs: 64*4096*256*2 B = 128 MiB
  float* fp = (float*)(wsb + (size_t)Bn * Nn * Dd * 2);
  float* slots = fp; fp += Bn * Ss * Dd;
  float* qk = fp;    fp += Bn * Ss * Dd;
  float* WqkT = fp;  fp += Dd * Dd;
  float* bqk = fp;   fp += Dd;
  float* pl = fp;    fp += Bn * CH * Ss;
  float* pu = fp;    fp += Bn * CH * Ss * Dd;
  (void)in_sizes; (void)n_in; (void)out_size; (void)ws_size;

  k_init<<<dim3(128), dim3(256), 0, stream>>>(noise, s_mu, s_sg, slots);
  k_wqk<<<dim3(257), dim3(256), 0, stream>>>(Wq, Wk, bq, WqkT, bqk);
  k_qk_only<<<dim3(128), dim3(512), 0, stream>>>(slots, gsl, bsl, WqkT, bqk, qk);
  for (int it = 0; it < 3; ++it) {
    if (it == 0)
      k_attn<true><<<dim3(CH, Bn), dim3(256), 0, stream>>>(inputs, xbf, qk, pl, pu);
    else
      k_attn<false><<<dim3(CH, Bn), dim3(256), 0, stream>>>(nullptr, xbf, qk, pl, pu);
    k_gru<<<dim3(128), dim3(512), 0, stream>>>(pl, pu, Wv, bv, Wih, bih, Whh, bhh, slots);
    k_mlp<<<dim3(128), dim3(512), 0, stream>>>(W1, b1, W2, b2, gml, bml, gsl, bsl, WqkT,
                                               bqk, slots, qk, (it == 2) ? out : nullptr);
  }
}

// Round 4
// 682.251 us; speedup vs baseline: 1.4891x; 1.3473x over previous
//
#include <hip/hip_runtime.h>

// SlotAttention, algebraically restructured:
//   logits = (LN(slots) @ (Wq^T @ Wk)) . x / 16   (q.bk term dropped: softmax-invariant)
//   updates = softmax-weighted-avg(x) @ Wv^T + bv  (attn rows sum to 1)
// -> k, v never materialized. x converted to bf16 once (L3-resident for iters 2,3).
// R2: attention on MFMA (16x16x32 bf16).
// R3: fused slot-update MFMA kernel; bf16 weights; attn double-buffer+prefetch. (crashed)
// R4: k_upd rebuilt: r/z/i_n/h_n fused in C-layout registers (no LDS round-trip),
//     static LDS 58.4 KB (<64K); __align__(16) on all LDS vector-accessed arrays.

constexpr int Bn = 64;    // batch
constexpr int Nn = 4096;  // inputs per batch
constexpr int Dd = 256;   // feature dim (== IN_D)
constexpr int Ss = 8;     // slots
constexpr int CH = 16;    // N-chunks per batch for attention
constexpr float EPSF = 1e-5f;

#define DEV __device__ __forceinline__

using short8 = __attribute__((ext_vector_type(8))) short;
using f32x4 = __attribute__((ext_vector_type(4))) float;
union U8 { short8 s; uint4 u; };

DEV unsigned bfpack2(float lo, float hi) {
  unsigned ul = __float_as_uint(lo), uh = __float_as_uint(hi);
  ul = (ul + 0x7FFFu + ((ul >> 16) & 1u)) >> 16;         // RNE to bf16
  uh = (uh + 0x7FFFu + ((uh >> 16) & 1u)) & 0xFFFF0000u;
  return ul | uh;
}
DEV unsigned short bf16r(float x) {
  unsigned u = __float_as_uint(x);
  u = (u + 0x7FFFu + ((u >> 16) & 1u)) >> 16;
  return (unsigned short)u;
}
DEV float rsum32(float v) {  // sum within each 32-lane half of a wave
  v += __shfl_xor(v, 1); v += __shfl_xor(v, 2); v += __shfl_xor(v, 4);
  v += __shfl_xor(v, 8); v += __shfl_xor(v, 16);
  return v;
}
DEV float sigm(float x) { return 1.f / (1.f + __expf(-x)); }

// ---- MFMA tile helpers: C[row=quad*4+r][col=t*16+m16] = sum_k A[row][k] W[col][k] + b
template <int NK>
DEV void load_af(short8* a, const unsigned short* base, int lda, int m16, int quad) {
  const unsigned short* p = base + m16 * lda + quad * 8;
#pragma unroll
  for (int kk = 0; kk < NK; ++kk) a[kk] = *(const short8*)(p + kk * 32);
}
template <int NK>
DEV f32x4 gemm_tile(const short8* a, const unsigned short* wr, float binit) {
  f32x4 acc = {binit, binit, binit, binit};
#pragma unroll
  for (int kk = 0; kk < NK; ++kk) {
    short8 b = *(const short8*)(wr + kk * 32);
    acc = __builtin_amdgcn_mfma_f32_16x16x32_bf16(a[kk], b, acc, 0, 0, 0);
  }
  return acc;
}

// LayerNorm over one 256-row held 8-per-thread by 32 lanes; writes bf16 packed out.
DEV void ln_row8(const float* x, const float* g, const float* b, int d0,
                 unsigned short* dst) {
  float s = x[0] + x[1] + x[2] + x[3] + x[4] + x[5] + x[6] + x[7];
  float mu = rsum32(s) * (1.f / 256.f);
  float q = 0.f;
#pragma unroll
  for (int j = 0; j < 8; ++j) { float d = x[j] - mu; q += d * d; }
  float rs = rsqrtf(rsum32(q) * (1.f / 256.f) + EPSF);
  float o[8];
#pragma unroll
  for (int j = 0; j < 8; ++j) o[j] = (x[j] - mu) * rs * g[d0 + j] + b[d0 + j];
  uint4 w;
  w.x = bfpack2(o[0], o[1]); w.y = bfpack2(o[2], o[3]);
  w.z = bfpack2(o[4], o[5]); w.w = bfpack2(o[6], o[7]);
  *(uint4*)dst = w;
}

// ---------------- init slots = mu + sigma*noise ----------------
__global__ __launch_bounds__(256) void k_init(const float* __restrict__ noise,
                                              const float* __restrict__ mu,
                                              const float* __restrict__ sg,
                                              float* __restrict__ slots) {
  int i = blockIdx.x * 256 + threadIdx.x;
  float4 nz = ((const float4*)noise)[i];
  int m = i & 511;
  float4 m4 = ((const float4*)mu)[m];
  float4 s4 = ((const float4*)sg)[m];
  float4 o;
  o.x = m4.x + s4.x * nz.x; o.y = m4.y + s4.y * nz.y;
  o.z = m4.z + s4.z * nz.z; o.w = m4.w + s4.w * nz.w;
  ((float4*)slots)[i] = o;
}

// ---------------- WqkT[c][d] = sum_e Wq[e][d]*Wk[e][c]; bqk[c] = sum_e bq[e]*Wk[e][c] ----
__global__ __launch_bounds__(256) void k_wqk(const float* __restrict__ Wq,
                                             const float* __restrict__ Wk,
                                             const float* __restrict__ bq,
                                             float* __restrict__ WqkT,
                                             float* __restrict__ bqk) {
  int tid = threadIdx.x, c = blockIdx.x;
  if (c < 256) {
    float acc = 0.f;
    for (int e = 0; e < 256; ++e) acc += Wq[e * 256 + tid] * Wk[e * 256 + c];
    WqkT[c * 256 + tid] = acc;
  } else {
    float acc = 0.f;
    for (int e = 0; e < 256; ++e) acc += bq[e] * Wk[e * 256 + tid];
    bqk[tid] = acc;
  }
}

// ---------------- convert weights to bf16 (+ zr-cat + bzr) ----------------
__global__ __launch_bounds__(256) void k_conv(
    const float* __restrict__ Wv, const float* __restrict__ Wih,
    const float* __restrict__ Whh, const float* __restrict__ W1,
    const float* __restrict__ W2, const float* __restrict__ WqkT,
    const float* __restrict__ bih, const float* __restrict__ bhh,
    unsigned* Wv_b, unsigned* Wzr_b, unsigned* Win_b, unsigned* Whn_b,
    unsigned* W1_b, unsigned* W2_b, unsigned* Wqk_b, float* bzr) {
  if (blockIdx.x >= 1280) {
    int i = (blockIdx.x - 1280) * 256 + threadIdx.x;
    if (i < 512) bzr[i] = bih[i] + bhh[i];
    return;
  }
  int p = blockIdx.x * 256 + threadIdx.x;  // bf16-pair index
  const float* src; unsigned* dst;
  if (p < 32768) { src = Wv + 2 * p; dst = Wv_b + p; }
  else if (p < 163840) {
    int q = p - 32768, row = q >> 8, col = (q & 255) * 2;
    src = (col < 256) ? (Wih + row * 256 + col) : (Whh + row * 256 + col - 256);
    dst = Wzr_b + q;
  }
  else if (p < 196608) { int q = p - 163840; src = Wih + 512 * 256 + 2 * q; dst = Win_b + q; }
  else if (p < 229376) { int q = p - 196608; src = Whh + 512 * 256 + 2 * q; dst = Whn_b + q; }
  else if (p < 262144) { int q = p - 229376; src = W1 + 2 * q; dst = W1_b + q; }
  else if (p < 294912) { int q = p - 262144; src = W2 + 2 * q; dst = W2_b + q; }
  else { int q = p - 294912; src = WqkT + 2 * q; dst = Wqk_b + q; }
  dst[0] = bfpack2(src[0], src[1]);
}

// ---------------- initial q' = (LN(slots)@WqkT + bqk)/16 ----------------
__global__ __launch_bounds__(512) void k_qk0(const float* __restrict__ slots,
                                             const float* __restrict__ gsl,
                                             const float* __restrict__ bsl,
                                             const unsigned short* __restrict__ Wqk_b,
                                             const float* __restrict__ bqk,
                                             float* __restrict__ qk) {
  __shared__ __align__(16) unsigned short lnb[16 * 264];
  const int tid = threadIdx.x, bb = blockIdx.x;
  const int lane = tid & 63, wave = tid >> 6;
  const int m16 = lane & 15, quad = lane >> 4;
  const int row = tid >> 5, l32 = tid & 31, d0 = l32 * 8;
  {
    const float* sp = slots + (size_t)(bb * 16 + row) * 256 + d0;
    float4 v0 = *(const float4*)sp, v1 = *(const float4*)(sp + 4);
    float x[8] = {v0.x, v0.y, v0.z, v0.w, v1.x, v1.y, v1.z, v1.w};
    ln_row8(x, gsl, bsl, d0, lnb + row * 264 + d0);
  }
  __syncthreads();
  short8 a8[8];
  load_af<8>(a8, lnb, 264, m16, quad);
#pragma unroll
  for (int i = 0; i < 2; ++i) {
    int t = wave + 8 * i;
    f32x4 acc = gemm_tile<8>(a8, Wqk_b + (size_t)(t * 16 + m16) * 256 + quad * 8,
                             bqk[t * 16 + m16]);
#pragma unroll
    for (int r = 0; r < 4; ++r)
      qk[(size_t)(bb * 16 + quad * 4 + r) * 256 + t * 16 + m16] = acc[r] * 0.0625f;
  }
}

// ---------------- MFMA attention pass ----------------
template <bool FIRST>
DEV void ld_chunk(const float* __restrict__ xin, unsigned* __restrict__ xbf,
                  size_t nbase, int tid, uint4* pr) {
#pragma unroll
  for (int i = 0; i < 4; ++i) {
    int flat = i * 256 + tid, n = flat >> 5, od = flat & 31;
    if (FIRST) {
      const float4* src = (const float4*)(xin + (nbase + n) * 256 + od * 8);
      float4 v0 = src[0], v1 = src[1];
      uint4 o;
      o.x = bfpack2(v0.x, v0.y); o.y = bfpack2(v0.z, v0.w);
      o.z = bfpack2(v1.x, v1.y); o.w = bfpack2(v1.z, v1.w);
      ((uint4*)xbf)[(nbase + n) * 32 + od] = o;
      pr[i] = o;
    } else {
      pr[i] = ((const uint4*)xbf)[(nbase + n) * 32 + od];
    }
  }
}

template <bool FIRST>
__global__ __launch_bounds__(256) void k_attn(const float* __restrict__ xin,
                                              unsigned* __restrict__ xbf,
                                              const float* __restrict__ qk,
                                              float* __restrict__ pl,
                                              float* __restrict__ pu) {
  __shared__ __align__(16) unsigned xt[2][128 * 33];
  __shared__ __align__(16) unsigned pp[16 * 17];
  __shared__ __align__(16) float lred[2][16];
  const int tid = threadIdx.x;
  const int lane = tid & 63, wave = tid >> 6;
  const int m16 = lane & 15, quad = lane >> 4;
  const int c = blockIdx.x, b = blockIdx.y;
  const int pb = (b * CH + c) * 8;

  // q A-frags: lane holds q[s=m16][k=quad*8+j]; s>=8 -> zero
  short8 aq[8];
  {
    const float* qrow = qk + (size_t)(b * 8 + (m16 & 7)) * 256 + quad * 8;
#pragma unroll
    for (int kk = 0; kk < 8; ++kk) {
      U8 f;
      float4 q0 = *(const float4*)(qrow + kk * 32);
      float4 q1 = *(const float4*)(qrow + kk * 32 + 4);
      f.u.x = bfpack2(q0.x, q0.y); f.u.y = bfpack2(q0.z, q0.w);
      f.u.z = bfpack2(q1.x, q1.y); f.u.w = bfpack2(q1.z, q1.w);
      if (m16 >= 8) { f.u.x = 0u; f.u.y = 0u; f.u.z = 0u; f.u.w = 0u; }
      aq[kk] = f.s;
    }
  }
  float lacc[4] = {0.f, 0.f, 0.f, 0.f};
  f32x4 acc[4];
#pragma unroll
  for (int t = 0; t < 4; ++t) acc[t] = (f32x4){0.f, 0.f, 0.f, 0.f};
  const int d0w = wave * 64;

  uint4 pr[4];
  ld_chunk<FIRST>(xin, xbf, (size_t)b * Nn + (size_t)c * 256, tid, pr);

  for (int ch = 0; ch < 8; ++ch) {
    unsigned* xtb = xt[ch & 1];
    // ---- stage from regs: X^T pair-packed [pair-d][33] ----
#pragma unroll
    for (int i = 0; i < 4; ++i) {
      int flat = i * 256 + tid, n = flat >> 5, od = flat & 31, rb = od * 4;
      xtb[(rb + 0) * 33 + n] = pr[i].x;
      xtb[(rb + 1) * 33 + n] = pr[i].y;
      xtb[(rb + 2) * 33 + n] = pr[i].z;
      xtb[(rb + 3) * 33 + n] = pr[i].w;
    }
    __syncthreads();
    if (ch < 7)  // prefetch next chunk (overlaps phase A/B)
      ld_chunk<FIRST>(xin, xbf, (size_t)b * Nn + (size_t)c * 256 + (ch + 1) * 32, tid, pr);
    // ---- phase A: P^T = q @ X^T, exp, l-partials ----
    if (wave < 2) {
      f32x4 pacc = (f32x4){0.f, 0.f, 0.f, 0.f};
#pragma unroll
      for (int kk = 0; kk < 8; ++kk) {
        int base = (kk * 16 + quad * 4) * 33 + wave * 16 + m16;
        U8 bf;
        bf.u.x = xtb[base]; bf.u.y = xtb[base + 33];
        bf.u.z = xtb[base + 66]; bf.u.w = xtb[base + 99];
        pacc = __builtin_amdgcn_mfma_f32_16x16x32_bf16(aq[kk], bf.s, pacc, 0, 0, 0);
      }
      const int xrow = wave * 16 + m16;
      unsigned short* pps = (unsigned short*)pp;
#pragma unroll
      for (int r = 0; r < 4; ++r) {
        float p = __expf(pacc[r]);  // |logit| small: no max-shift needed
        lacc[r] += p;
        pps[((xrow >> 1) * 17 + quad * 4 + r) * 2 + (xrow & 1)] = bf16r(p);
      }
    }
    __syncthreads();
    // ---- phase B: U^T += X^T @ P ----
    U8 bp;
    bp.u.x = pp[(quad * 4 + 0) * 17 + m16];
    bp.u.y = pp[(quad * 4 + 1) * 17 + m16];
    bp.u.z = pp[(quad * 4 + 2) * 17 + m16];
    bp.u.w = pp[(quad * 4 + 3) * 17 + m16];
#pragma unroll
    for (int t = 0; t < 4; ++t) {
      int d = d0w + t * 16 + m16;
      int h = d >> 1, sel = d & 1;
      const unsigned* xr = xtb + h * 33 + quad * 8;
      unsigned u0 = xr[0], u1 = xr[1], u2 = xr[2], u3 = xr[3];
      unsigned u4 = xr[4], u5 = xr[5], u6 = xr[6], u7 = xr[7];
      U8 af;
      if (sel) {
        af.u.x = (u0 >> 16) | (u1 & 0xFFFF0000u);
        af.u.y = (u2 >> 16) | (u3 & 0xFFFF0000u);
        af.u.z = (u4 >> 16) | (u5 & 0xFFFF0000u);
        af.u.w = (u6 >> 16) | (u7 & 0xFFFF0000u);
      } else {
        af.u.x = (u0 & 0xFFFFu) | (u1 << 16);
        af.u.y = (u2 & 0xFFFFu) | (u3 << 16);
        af.u.z = (u4 & 0xFFFFu) | (u5 << 16);
        af.u.w = (u6 & 0xFFFFu) | (u7 << 16);
      }
      acc[t] = __builtin_amdgcn_mfma_f32_16x16x32_bf16(af.s, bp.s, acc[t], 0, 0, 0);
    }
    __syncthreads();
  }
  if (m16 < 8) {
#pragma unroll
    for (int t = 0; t < 4; ++t)
#pragma unroll
      for (int r = 0; r < 4; ++r)
        pu[(size_t)(pb + m16) * 256 + d0w + t * 16 + quad * 4 + r] = acc[t][r];
  }
  if (wave < 2) {
#pragma unroll
    for (int r = 0; r < 4; ++r) {
      float v = lacc[r];
      v += __shfl_xor(v, 1); v += __shfl_xor(v, 2);
      v += __shfl_xor(v, 4); v += __shfl_xor(v, 8);
      if (m16 == 0) lred[wave][quad * 4 + r] = v;
    }
  }
  __syncthreads();
  if (tid < 8) pl[pb + tid] = lred[0][tid] + lred[1][tid];
}

// ---------------- fused slot update: combine+Wv+GRU+MLP+LN+next-q' ----------------
// 32 blocks x 512 threads; block = 16 rows (2 batches x 8 slots).
// GRU gates fused in C-layout registers: wave w owns output cols of tiles {w, w+8}
// for r, z, i_n, h_n alike -> no LDS round-trip for gates. Static LDS = 58.4 KB.
__global__ __launch_bounds__(512) void k_upd(
    const float* __restrict__ pl, const float* __restrict__ pu,
    const unsigned short* __restrict__ Wv_b, const float* __restrict__ bv,
    const unsigned short* __restrict__ Wzr_b, const float* __restrict__ bzr,
    const unsigned short* __restrict__ Win_b, const float* __restrict__ bin,
    const unsigned short* __restrict__ Whn_b, const float* __restrict__ bhn,
    const unsigned short* __restrict__ W1_b, const float* __restrict__ b1,
    const unsigned short* __restrict__ W2_b, const float* __restrict__ b2,
    const float* __restrict__ gml, const float* __restrict__ bml,
    const float* __restrict__ gsl, const float* __restrict__ bsl,
    const unsigned short* __restrict__ Wqk_b, const float* __restrict__ bqk,
    float* __restrict__ slots, float* __restrict__ qk, float* __restrict__ dout) {
  __shared__ __align__(16) unsigned short cat[16 * 520];  // [u'|h] -> [upd|h]; hid in [0:256)
  __shared__ __align__(16) float sp[16 * 260];            // h_prev; later slots2
  __shared__ __align__(16) float s1[16 * 260];            // slots1 (post-GRU residual)
  __shared__ __align__(16) unsigned short lnb[16 * 264];  // LN output bf16 (A operand)
  const int tid = threadIdx.x, bb = blockIdx.x;
  const int lane = tid & 63, wave = tid >> 6;
  const int m16 = lane & 15, quad = lane >> 4;
  const int row = tid >> 5, l32 = tid & 31, d0 = l32 * 8;
  const int bat = 2 * bb + (row >> 3), sl = row & 7;
  // ---- 1: combine chunk partials -> u' bf16; h_prev -> sp f32 + cat bf16 ----
  {
    float L = 0.f;
#pragma unroll
    for (int cc = 0; cc < 16; ++cc) L += pl[(bat * 16 + cc) * 8 + sl];
    float li = 1.f / L;
    float a[8] = {0.f, 0.f, 0.f, 0.f, 0.f, 0.f, 0.f, 0.f};
    for (int cc = 0; cc < 16; ++cc) {
      const float* pp_ = pu + ((size_t)(bat * 16 + cc) * 8 + sl) * 256 + d0;
      float4 v0 = *(const float4*)pp_, v1 = *(const float4*)(pp_ + 4);
      a[0] += v0.x; a[1] += v0.y; a[2] += v0.z; a[3] += v0.w;
      a[4] += v1.x; a[5] += v1.y; a[6] += v1.z; a[7] += v1.w;
    }
    uint4 o;
    o.x = bfpack2(a[0] * li, a[1] * li); o.y = bfpack2(a[2] * li, a[3] * li);
    o.z = bfpack2(a[4] * li, a[5] * li); o.w = bfpack2(a[6] * li, a[7] * li);
    *(uint4*)(cat + row * 520 + d0) = o;
    const float* sp_ = slots + (size_t)(bb * 16 + row) * 256 + d0;
    float4 h0 = *(const float4*)sp_, h1 = *(const float4*)(sp_ + 4);
    *(float4*)(sp + row * 260 + d0) = h0;
    *(float4*)(sp + row * 260 + d0 + 4) = h1;
    uint4 hb;
    hb.x = bfpack2(h0.x, h0.y); hb.y = bfpack2(h0.z, h0.w);
    hb.z = bfpack2(h1.x, h1.y); hb.w = bfpack2(h1.z, h1.w);
    *(uint4*)(cat + row * 520 + 256 + d0) = hb;
  }
  __syncthreads();
  // ---- 2: updates = u' @ Wv^T + bv (regs), then -> cat[:,0:256) bf16 ----
  short8 afr[16];
  load_af<8>(afr, cat, 520, m16, quad);
  f32x4 accv[2];
#pragma unroll
  for (int i = 0; i < 2; ++i) {
    int t = wave + 8 * i;
    accv[i] = gemm_tile<8>(afr, Wv_b + (size_t)(t * 16 + m16) * 256 + quad * 8,
                           bv[t * 16 + m16]);
  }
  __syncthreads();
#pragma unroll
  for (int i = 0; i < 2; ++i) {
    int t = wave + 8 * i;
#pragma unroll
    for (int r = 0; r < 4; ++r)
      cat[(quad * 4 + r) * 520 + t * 16 + m16] = bf16r(accv[i][r]);
  }
  __syncthreads();
  // ---- 3: r,z = sigmoid([upd|h] @ Wzr^T + bzr), kept in C-layout regs ----
  load_af<16>(afr, cat, 520, m16, quad);
  f32x4 rr[2], zz[2];
#pragma unroll
  for (int i = 0; i < 2; ++i) {
    int t = wave + 8 * i;
    f32x4 ar = gemm_tile<16>(afr, Wzr_b + (size_t)(t * 16 + m16) * 512 + quad * 8,
                             bzr[t * 16 + m16]);
    f32x4 az = gemm_tile<16>(afr, Wzr_b + (size_t)((t + 16) * 16 + m16) * 512 + quad * 8,
                             bzr[(t + 16) * 16 + m16]);
#pragma unroll
    for (int r = 0; r < 4; ++r) { rr[i][r] = sigm(ar[r]); zz[i][r] = sigm(az[r]); }
  }
  // ---- 4: i_n, h_n (same cols as r,z) -> gate fused in regs -> s1 ----
#pragma unroll
  for (int i = 0; i < 2; ++i) {
    int t = wave + 8 * i, col = t * 16 + m16;
    f32x4 ain = gemm_tile<8>(afr, Win_b + (size_t)(t * 16 + m16) * 256 + quad * 8,
                             bin[col]);
    f32x4 ahn = gemm_tile<8>(afr + 8, Whn_b + (size_t)(t * 16 + m16) * 256 + quad * 8,
                             bhn[col]);
#pragma unroll
    for (int r = 0; r < 4; ++r) {
      int rw = quad * 4 + r;
      float nin = ain[r] + rr[i][r] * ahn[r];
      float nn = 1.f - 2.f / (__expf(2.f * nin) + 1.f);  // tanh
      float hpc = sp[rw * 260 + col];
      s1[rw * 260 + col] = hpc + (1.f - zz[i][r]) * nn + zz[i][r] * hpc;  // prev + h_new
    }
  }
  __syncthreads();
  // ---- 5: LN_mlp(slots1) -> lnb ----
  {
    const float* s1r = s1 + row * 260 + d0;
    float4 v0 = *(const float4*)s1r, v1 = *(const float4*)(s1r + 4);
    float x[8] = {v0.x, v0.y, v0.z, v0.w, v1.x, v1.y, v1.z, v1.w};
    ln_row8(x, gml, bml, d0, lnb + row * 264 + d0);
  }
  __syncthreads();
  // ---- 6: hid = relu(LN_mlp @ W1^T + b1) -> cat[:,0:256) ----
  load_af<8>(afr, lnb, 264, m16, quad);
#pragma unroll
  for (int i = 0; i < 2; ++i) {
    int t = wave + 8 * i;
    f32x4 acc = gemm_tile<8>(afr, W1_b + (size_t)(t * 16 + m16) * 256 + quad * 8,
                             b1[t * 16 + m16]);
#pragma unroll
    for (int r = 0; r < 4; ++r)
      cat[(quad * 4 + r) * 520 + t * 16 + m16] = bf16r(fmaxf(acc[r], 0.f));
  }
  __syncthreads();
  // ---- 7: slots2 = slots1 + hid @ W2^T + b2 -> global + sp(reuse) ----
  load_af<8>(afr, cat, 520, m16, quad);
#pragma unroll
  for (int i = 0; i < 2; ++i) {
    int t = wave + 8 * i;
    f32x4 acc = gemm_tile<8>(afr, W2_b + (size_t)(t * 16 + m16) * 256 + quad * 8,
                             b2[t * 16 + m16]);
#pragma unroll
    for (int r = 0; r < 4; ++r) {
      int rw = quad * 4 + r, col = t * 16 + m16;
      float v = acc[r] + s1[rw * 260 + col];
      size_t gi = (size_t)(bb * 16 + rw) * 256 + col;
      slots[gi] = v;
      if (dout) dout[gi] = v;
      sp[rw * 260 + col] = v;
    }
  }
  __syncthreads();
  // ---- 8: LN_slots(slots2) -> lnb ----
  {
    const float* spr = sp + row * 260 + d0;
    float4 v0 = *(const float4*)spr, v1 = *(const float4*)(spr + 4);
    float x[8] = {v0.x, v0.y, v0.z, v0.w, v1.x, v1.y, v1.z, v1.w};
    ln_row8(x, gsl, bsl, d0, lnb + row * 264 + d0);
  }
  __syncthreads();
  // ---- 9: q' = (LN_slots @ WqkT + bqk)/16 ----
  load_af<8>(afr, lnb, 264, m16, quad);
#pragma unroll
  for (int i = 0; i < 2; ++i) {
    int t = wave + 8 * i;
    f32x4 acc = gemm_tile<8>(afr, Wqk_b + (size_t)(t * 16 + m16) * 256 + quad * 8,
                             bqk[t * 16 + m16]);
#pragma unroll
    for (int r = 0; r < 4; ++r)
      qk[(size_t)(bb * 16 + quad * 4 + r) * 256 + t * 16 + m16] = acc[r] * 0.0625f;
  }
}

// ---------------- launch ----------------
extern "C" void kernel_launch(void* const* d_in, const int* in_sizes, int n_in,
                              void* d_out, int out_size, void* d_ws, size_t ws_size,
                              hipStream_t stream) {
  const float* inputs = (const float*)d_in[0];
  const float* noise = (const float*)d_in[1];
  const float* s_mu = (const float*)d_in[2];
  const float* s_sg = (const float*)d_in[3];
  const float* Wq = (const float*)d_in[4];
  const float* bq = (const float*)d_in[5];
  const float* Wk = (const float*)d_in[6];
  // d_in[7] = bk: unused (softmax-invariant)
  const float* Wv = (const float*)d_in[8];
  const float* bv = (const float*)d_in[9];
  const float* Wih = (const float*)d_in[10];
  const float* bih = (const float*)d_in[11];
  const float* Whh = (const float*)d_in[12];
  const float* bhh = (const float*)d_in[13];
  const float* W1 = (const float*)d_in[14];
  const float* b1 = (const float*)d_in[15];
  const float* W2 = (const float*)d_in[16];
  const float* b2 = (const float*)d_in[17];
  const float* gsl = (const float*)d_in[18];
  const float* bsl = (const float*)d_in[19];
  const float* gml = (const float*)d_in[20];
  const float* bml = (const float*)d_in[21];
  float* out = (float*)d_out;

  char* wsb = (char*)d_ws;
  unsigned* xbf = (unsigned*)wsb;  // bf16 copy of inputs: 128 MiB
  float* fp = (float*)(wsb + (size_t)Bn * Nn * Dd * 2);
  float* slots = fp; fp += Bn * Ss * Dd;
  float* qk = fp;    fp += Bn * Ss * Dd;
  float* WqkT = fp;  fp += Dd * Dd;
  float* bqk = fp;   fp += Dd;
  float* pl = fp;    fp += Bn * CH * Ss;
  float* pu = fp;    fp += Bn * CH * Ss * Dd;
  float* bzr = fp;   fp += 512;
  unsigned short* wb = (unsigned short*)fp;
  unsigned short* Wv_b = wb;  wb += 65536;
  unsigned short* Wzr_b = wb; wb += 262144;
  unsigned short* Win_b = wb; wb += 65536;
  unsigned short* Whn_b = wb; wb += 65536;
  unsigned short* W1_b = wb;  wb += 65536;
  unsigned short* W2_b = wb;  wb += 65536;
  unsigned short* Wqk_b = wb; wb += 65536;
  (void)in_sizes; (void)n_in; (void)out_size; (void)ws_size;

  k_init<<<dim3(128), dim3(256), 0, stream>>>(noise, s_mu, s_sg, slots);
  k_wqk<<<dim3(257), dim3(256), 0, stream>>>(Wq, Wk, bq, WqkT, bqk);
  k_conv<<<dim3(1282), dim3(256), 0, stream>>>(
      Wv, Wih, Whh, W1, W2, WqkT, bih, bhh, (unsigned*)Wv_b, (unsigned*)Wzr_b,
      (unsigned*)Win_b, (unsigned*)Whn_b, (unsigned*)W1_b, (unsigned*)W2_b,
      (unsigned*)Wqk_b, bzr);
  k_qk0<<<dim3(32), dim3(512), 0, stream>>>(slots, gsl, bsl, Wqk_b, bqk, qk);
  for (int it = 0; it < 3; ++it) {
    if (it == 0)
      k_attn<true><<<dim3(CH, Bn), dim3(256), 0, stream>>>(inputs, xbf, qk, pl, pu);
    else
      k_attn<false><<<dim3(CH, Bn), dim3(256), 0, stream>>>(nullptr, xbf, qk, pl, pu);
    k_upd<<<dim3(32), dim3(512), 0, stream>>>(
        pl, pu, Wv_b, bv, Wzr_b, bzr, Win_b, bih + 512, Whn_b, bhh + 512, W1_b, b1,
        W2_b, b2, gml, bml, gsl, bsl, Wqk_b, bqk, slots, qk, (it == 2) ? out : nullptr);
  }
}